// Round 11
// baseline (2623.623 us; speedup 1.0000x reference)
//
#include <hip/hip_runtime.h>
#include <cstdint>
#include <cstddef>
#include <cmath>

#define H  2048
#define BB 2048   // batch
#define TT 64     // time steps
#define NC 10     // classes

typedef __bf16 bf16;
typedef bf16  bf16x8 __attribute__((ext_vector_type(8)));
typedef float f32x4  __attribute__((ext_vector_type(4)));

// ---------------------------------------------------------------------------
// FRAG-MAJOR layout (both operands). For a matrix M[rows][K]:
// subtile (r16, k32) = 16 rows x 32 k = 512 bf16 (1 KB), id = r16*(H/32) + k32.
// Lane-slot l (16 B) holds M[r16*16 + (l&15)][k32*32 + (l>>4)*8 .. +8] —
// exactly the v_mfma_f32_16x16x32_bf16 A- or B-operand fragment, so a wave's
// frag load is ONE coalesced 1 KB segment: base + id*512 + lane*8.
// Element (b, h) lives at:
// ---------------------------------------------------------------------------
__device__ __forceinline__ size_t fa(int b, int h) {
    return ((size_t)((b >> 4) * (H / 32) + (h >> 5)) << 9)   // subtile * 512
         + ((size_t)((b & 15) + (((h & 31) >> 3) << 4)) << 3) // slot * 8
         + (h & 7);
}

// ---------------------------------------------------------------------------
// W_hh fp32 -> bf16 into frag-major layout (unchanged from R9/R10).
// ---------------------------------------------------------------------------
__global__ void w_shuffle_kernel(const float* __restrict__ Whh,
                                 bf16* __restrict__ Wshuf) {
    int tid = blockIdx.x * blockDim.x + threadIdx.x;   // 0 .. H*H/8-1
    int sub = tid >> 6;          // subtile id
    int l   = tid & 63;          // dest lane slot
    int n16 = sub >> 6;          // 0..127
    int k32 = sub & 63;          // 0..63
    int n = n16 * 16 + (l & 15);
    int k = k32 * 32 + (l >> 4) * 8;
    const float* src = Whh + (size_t)n * H + k;
    bf16x8 o;
#pragma unroll
    for (int j = 0; j < 8; ++j) o[j] = (bf16)src[j];
    *(bf16x8*)(Wshuf + (size_t)tid * 8) = o;
}

// ---------------------------------------------------------------------------
// t = 0: S[b,i] = tanh(Whx[i]*x[b,0] + bh[i]), written FRAG-MAJOR.
// 8 consecutive h share one slot -> contiguous bf16x8 store.
// ---------------------------------------------------------------------------
__global__ void rnn_init(const float* __restrict__ x,     // [B, T]
                         const float* __restrict__ Whx,   // [H]
                         const float* __restrict__ bh,    // [H]
                         bf16* __restrict__ S) {          // frag-major
    int b  = blockIdx.x;
    int i0 = threadIdx.x * 8;
    float xv = x[(size_t)b * TT];
    bf16x8 o;
#pragma unroll
    for (int j = 0; j < 8; ++j)
        o[j] = (bf16)tanhf(Whx[i0 + j] * xv + bh[i0 + j]);
    *(bf16x8*)(S + fa(b, i0)) = o;
}

// ---------------------------------------------------------------------------
// One RNN time step — BARRIER-FREE, LDS-FREE.
//
// Round-11 insight: the k-loop barrier existed only because A (state S)
// transited LDS. Storing S itself in A-frag-major layout (the epilogue is
// ours to define) lets BOTH operands load as coalesced 1 KB wave-segments
// straight into VGPRs. No LDS, no __syncthreads, no vmcnt(0) drains: the
// compiler is free to software-pipeline MFMA <-> buffer_load with
// fine-grained s_waitcnt vmcnt(N) — the AITER-style K-loop that barrier
// structures cannot express (R10 capped pipeline depth at 1 iter).
//
// Geometry unchanged: 128(m) x 64(n), grid 512 (2 blocks/CU), bm-XCD map
// (S slice 1 MB -> XCD-local L2, producer-consumer locality across steps).
// Per k32-chunk per wave: 4 A-frag + 2 B-frag loads, 8 MFMAs (~1:1 ratio).
// Depth-2 register ping-pong, compute-then-prefetch, fully unrolled.
// ---------------------------------------------------------------------------
__launch_bounds__(256)
__global__ void rnn_step(const float* __restrict__ x,     // [B, T]
                         const float* __restrict__ Whx,   // [H]
                         const float* __restrict__ bh,    // [H]
                         const bf16*  __restrict__ Wshuf, // frag-major W
                         const bf16*  __restrict__ Sr,    // frag-major S read
                         bf16* __restrict__ Sw,           // frag-major S write
                         int t) {
    const int tid  = threadIdx.x;
    const int w    = tid >> 6;          // wave 0..3
    const int lane = tid & 63;

    // XCD-aware mapping: XCD owns batch rows (S producer-consumer locality).
    const int xcd = blockIdx.x & 7;
    const int loc = blockIdx.x >> 3;              // 0..63
    const int bm0 = (xcd * 2 + (loc & 1)) * 128;  // batch-row tile origin
    const int bn0 = (loc >> 1) * 64;              // hidden-col tile origin

    const int qm   = (w & 1) * 64;               // wave m-quadrant (64 rows)
    const int qn   = (w >> 1) * 32;              // wave n-quadrant (32 cols)
    const int lrow = lane & 15;
    const int quad = lane >> 4;

    // frag-load bases: id = r16*64 + k32; bf16 offset = id*512 + lane*8
    const bf16* pa = Sr    + (size_t)lane * 8;
    const bf16* pb = Wshuf + (size_t)lane * 8;
    const int subA0 = ((bm0 + qm) >> 4) * 64;    // + fm*64 + k32
    const int subB0 = ((bn0 + qn) >> 4) * 64;    // + fn*64 + k32

    auto loadA = [&](bf16x8 (&A)[4], int k32) {
#pragma unroll
        for (int fm = 0; fm < 4; ++fm)
            A[fm] = *(const bf16x8*)(pa + ((size_t)(subA0 + fm * 64 + k32) << 9));
    };
    auto loadB = [&](bf16x8 (&B)[2], int k32) {
#pragma unroll
        for (int fn = 0; fn < 2; ++fn)
            B[fn] = *(const bf16x8*)(pb + ((size_t)(subB0 + fn * 64 + k32) << 9));
    };

    f32x4 acc[4][2];
#pragma unroll
    for (int i = 0; i < 4; ++i)
#pragma unroll
        for (int j = 0; j < 2; ++j) acc[i][j] = (f32x4){0.f, 0.f, 0.f, 0.f};

    bf16x8 Ab[2][4], Bb[2][2];
    loadA(Ab[0], 0); loadB(Bb[0], 0);
    loadA(Ab[1], 1); loadB(Bb[1], 1);

#pragma unroll
    for (int k = 0; k < H / 32; ++k) {
        const int cur = k & 1;
#pragma unroll
        for (int fm = 0; fm < 4; ++fm)
#pragma unroll
            for (int fn = 0; fn < 2; ++fn)
                acc[fm][fn] = __builtin_amdgcn_mfma_f32_16x16x32_bf16(
                    Ab[cur][fm], Bb[cur][fn], acc[fm][fn], 0, 0, 0);
        if (k + 2 < H / 32) { loadA(Ab[cur], k + 2); loadB(Bb[cur], k + 2); }
    }

    // epilogue: z += Whx[i]*x[b,t] + bh[i]; tanh; store bf16 FRAG-MAJOR.
    // C layout (16x16x32): col = lane&15, row = quad*4 + reg  [m89-verified]
    // target element (b = rb+r, h = col):
    //   subtile = ((bm0+qm)>>4 + fm)*64 + ((bn0+qn)>>5)   [h>>5 wave-const]
    //   slot    = (quad*4 + r) + 16*(fn*2 + (lrow>>3)),  byte j = lrow&7
#pragma unroll
    for (int fm = 0; fm < 4; ++fm) {
        int rb = bm0 + qm + fm * 16 + quad * 4;
        size_t subb = ((size_t)(((bm0 + qm) >> 4) + fm) * 64 +
                       ((bn0 + qn) >> 5)) << 9;
        float xv[4];
#pragma unroll
        for (int r = 0; r < 4; ++r) xv[r] = x[(size_t)(rb + r) * TT + t];
#pragma unroll
        for (int fn = 0; fn < 2; ++fn) {
            int col = bn0 + qn + fn * 16 + lrow;
            float wx = Whx[col], bb = bh[col];
            int slotb = (quad * 4) + 16 * (fn * 2 + (lrow >> 3));
#pragma unroll
            for (int r = 0; r < 4; ++r) {
                float z = acc[fm][fn][r] + wx * xv[r] + bb;
                Sw[subb + (size_t)(slotb + r) * 8 + (lrow & 7)] = (bf16)tanhf(z);
            }
        }
    }
}

// ---------------------------------------------------------------------------
// out[b,c] = sum_h Why[h,c] * S[b,h] + bp[c]   (S frag-major)
// one block per batch row; thread tid covers h = tid*8 .. +8 (one chunk).
// ---------------------------------------------------------------------------
__global__ void out_proj(const bf16* __restrict__ S,
                         const float* __restrict__ Why,   // [H, C]
                         const float* __restrict__ bp,    // [C]
                         float* __restrict__ out) {       // [B, C]
    int b = blockIdx.x, tid = threadIdx.x;
    float p[NC];
#pragma unroll
    for (int c = 0; c < NC; ++c) p[c] = 0.f;
    int h0 = tid * 8;
    bf16x8 sv = *(const bf16x8*)(S + fa(b, h0));
#pragma unroll
    for (int j = 0; j < 8; ++j) {
        float s = (float)sv[j];
        const float* wr = Why + (size_t)(h0 + j) * NC;
#pragma unroll
        for (int c = 0; c < NC; ++c) p[c] += s * wr[c];
    }
    __shared__ float red[256 * NC];
#pragma unroll
    for (int c = 0; c < NC; ++c) red[tid * NC + c] = p[c];
    __syncthreads();
    for (int s = 128; s > 0; s >>= 1) {
        if (tid < s)
#pragma unroll
            for (int c = 0; c < NC; ++c) red[tid * NC + c] += red[(tid + s) * NC + c];
        __syncthreads();
    }
    if (tid < NC) out[(size_t)b * NC + tid] = red[tid] + bp[tid];
}

// ---------------------------------------------------------------------------
extern "C" void kernel_launch(void* const* d_in, const int* in_sizes, int n_in,
                              void* d_out, int out_size, void* d_ws, size_t ws_size,
                              hipStream_t stream) {
    const float* x   = (const float*)d_in[0];   // [B, T]
    const float* Whx = (const float*)d_in[1];   // [H, 1]
    const float* Whh = (const float*)d_in[2];   // [H, H]
    const float* Why = (const float*)d_in[3];   // [H, C]
    const float* bh  = (const float*)d_in[4];   // [H, 1]
    const float* bp  = (const float*)d_in[5];   // [C, 1]
    float* out = (float*)d_out;

    // workspace: Wshuf (8 MB) | S0 (8 MB) | S1 (8 MB)   (all frag-major)
    bf16* Wshuf = (bf16*)d_ws;
    bf16* S0 = (bf16*)((char*)d_ws + (size_t)8 * 1024 * 1024);
    bf16* S1 = (bf16*)((char*)d_ws + (size_t)16 * 1024 * 1024);

    hipLaunchKernelGGL(w_shuffle_kernel, dim3((H * H / 8) / 256), dim3(256),
                       0, stream, Whh, Wshuf);

    // t = 0 writes S1; step t reads (t&1 ? S1 : S0), writes the other.
    hipLaunchKernelGGL(rnn_init, dim3(BB), dim3(256), 0, stream, x, Whx, bh, S1);

    for (int t = 1; t < TT; ++t) {
        const bf16* Srd = (t & 1) ? S1 : S0;
        bf16*       Swr = (t & 1) ? S0 : S1;
        hipLaunchKernelGGL(rnn_step, dim3(512), dim3(256), 0, stream,
                           x, Whx, bh, Wshuf, Srd, Swr, t);
    }

    // t=63 (odd) wrote S0
    hipLaunchKernelGGL(out_proj, dim3(BB), dim3(256), 0, stream, S0, Why, bp, out);
}

// Round 12
// 1802.352 us; speedup vs baseline: 1.4557x; 1.4557x over previous
//
#include <hip/hip_runtime.h>
#include <cstdint>
#include <cstddef>
#include <cmath>

#define H  2048
#define BB 2048   // batch
#define TT 64     // time steps
#define NC 10     // classes
#define BK 128    // K-chunk per staging iter (16 x 16B chunks per row)

typedef __bf16 bf16;
typedef bf16  bf16x8 __attribute__((ext_vector_type(8)));
typedef float f32x4  __attribute__((ext_vector_type(4)));

// ---------------------------------------------------------------------------
// async global->LDS, 16B per lane. LDS dest is wave-uniform base + lane*16.
// ---------------------------------------------------------------------------
__device__ __forceinline__ void load_lds16(const void* g, void* l) {
    __builtin_amdgcn_global_load_lds(
        (__attribute__((address_space(1))) void*)(void*)g,
        (__attribute__((address_space(3))) void*)l,
        16, 0, 0);
}

// ---------------------------------------------------------------------------
// W_hh fp32 -> bf16, shuffled into MFMA-B-frag-major layout:
// subtile (n16, k32) = 16 n-rows x 32 k, 1024 B, at id = n16*64 + k32.
// Lane-slot l holds W[n16*16 + (l&15)][k32*32 + (l>>4)*8 .. +8] — exactly the
// v_mfma B-fragment, so a wave's B-frag load is ONE coalesced 1 KB segment.
// ---------------------------------------------------------------------------
__global__ void w_shuffle_kernel(const float* __restrict__ Whh,
                                 bf16* __restrict__ Wshuf) {
    int tid = blockIdx.x * blockDim.x + threadIdx.x;   // 0 .. H*H/8-1
    int sub = tid >> 6;          // subtile id
    int l   = tid & 63;          // dest lane slot
    int n16 = sub >> 6;          // 0..127
    int k32 = sub & 63;          // 0..63
    int n = n16 * 16 + (l & 15);
    int k = k32 * 32 + (l >> 4) * 8;
    const float* src = Whh + (size_t)n * H + k;
    bf16x8 o;
#pragma unroll
    for (int j = 0; j < 8; ++j) o[j] = (bf16)src[j];
    *(bf16x8*)(Wshuf + (size_t)tid * 8) = o;
}

// ---------------------------------------------------------------------------
// t = 0: S[b,i] = tanh(Whx[i]*x[b,0] + bh[i]).  One block per batch row.
// ---------------------------------------------------------------------------
__global__ void rnn_init(const float* __restrict__ x,     // [B, T]
                         const float* __restrict__ Whx,   // [H]
                         const float* __restrict__ bh,    // [H]
                         bf16* __restrict__ S) {          // [B, H]
    int b  = blockIdx.x;
    int i0 = threadIdx.x * 8;
    float xv = x[(size_t)b * TT];
    bf16x8 o;
#pragma unroll
    for (int j = 0; j < 8; ++j)
        o[j] = (bf16)tanhf(Whx[i0 + j] * xv + bh[i0 + j]);
    *(bf16x8*)(S + (size_t)b * H + i0) = o;
}

// ---------------------------------------------------------------------------
// One RNN time step. Round-12 = Round-10 (best, 1782 us) with BK 64 -> 128:
// 16 barriers/step instead of 32; each prefetch gets a ~2x compute phase in
// flight before the barrier that drains it. LDS 2 x 32 KB = 64 KB/block,
// 2 blocks/CU = 128 KB <= 160 KB pool (co-residency preserved).
//
// Structure (proven): 128(m) x 64(n) tile, grid 512 -> 2 blocks/CU (m114);
// A (state S) double-buffered in XOR-swizzled LDS (conflict-free); B (W_hh)
// loaded as coalesced 1 KB/wave frag-major segments straight to VGPRs
// (R11 showed A must stay in LDS: pure-VGPR operand double-loads A and the
// compiler drops the ping-pong, serializing L1 latency).
// Swizzle (16 chunks/row): LDS chunk l of row r holds global chunk
// (l&8)|((l^r)&7); frag-read lanes spread 8 bank-groups -> 2-way = free.
// ---------------------------------------------------------------------------
__launch_bounds__(256)
__global__ void rnn_step(const float* __restrict__ x,     // [B, T]
                         const float* __restrict__ Whx,   // [H]
                         const float* __restrict__ bh,    // [H]
                         const bf16*  __restrict__ Wshuf, // [H, H] frag-major
                         const bf16*  __restrict__ Sr,    // [B, H] read
                         bf16* __restrict__ Sw,           // [B, H] write
                         int t) {
    __shared__ __align__(16) bf16 As[2][128 * BK];  // 2 x 32 KB (S tile)

    const int tid  = threadIdx.x;
    const int w    = tid >> 6;          // wave 0..3
    const int lane = tid & 63;

    // XCD-aware mapping: XCD owns batch rows (S producer-consumer locality).
    const int xcd = blockIdx.x & 7;
    const int loc = blockIdx.x >> 3;              // 0..63
    const int bm0 = (xcd * 2 + (loc & 1)) * 128;  // batch-row tile origin
    const int bn0 = (loc >> 1) * 64;              // hidden-col tile origin

    const int qm   = (w & 1) * 64;               // wave m-quadrant (64 rows)
    const int qn   = (w >> 1) * 32;              // wave n-quadrant (32 cols)
    const int lrow = lane & 15;
    const int quad = lane >> 4;

    const int s_r16 = tid >> 4;                  // staging row within 16-group
    const int s_c   = tid & 15;                  // staging chunk in row (0..15)

    // B-frag source base: subtile id = n16*64 + k32; bf16 offset id*512+lane*8
    const int nb16 = (bn0 + qn) >> 4;            // n16 of fn=0 frag
    const bf16* wb = Wshuf + (size_t)lane * 8;

    // stage A K-chunk k0 (BK=128 wide) into LDS buffer b: 8 wave-instrs
    auto stageA = [&](int b, int k0) {
#pragma unroll
        for (int i = 0; i < 8; ++i) {
            int r = i * 16 + s_r16;               // tile row 0..127
            int g = (s_c & 8) | ((s_c ^ r) & 7);  // swizzled source chunk
            load_lds16(Sr + (size_t)(bm0 + r) * H + k0 + g * 8,
                       &As[b][(i * 256 + w * 64) * 8]);
        }
    };
    // load B frags for K-chunk k0 (4 k32-subchunks) into registers
    auto loadB = [&](bf16x8 (&B)[4][2], int k0) {
        const int kb32 = k0 >> 5;
#pragma unroll
        for (int kc = 0; kc < 4; ++kc)
#pragma unroll
            for (int fn = 0; fn < 2; ++fn)
                B[kc][fn] = *(const bf16x8*)(wb +
                    ((size_t)(nb16 + fn) * 64 + kb32 + kc) * 512);
    };

    f32x4 acc[4][2];
#pragma unroll
    for (int i = 0; i < 4; ++i)
#pragma unroll
        for (int j = 0; j < 2; ++j) acc[i][j] = (f32x4){0.f, 0.f, 0.f, 0.f};

    auto compute = [&](const bf16* Ab, bf16x8 (&B)[4][2]) {
#pragma unroll
        for (int kc = 0; kc < 4; ++kc) {
            bf16x8 af[4];
#pragma unroll
            for (int f = 0; f < 4; ++f) {
                int row = qm + f * 16 + lrow;
                int g   = kc * 4 + quad;
                int l   = (g & 8) | ((g ^ row) & 7);
                af[f] = *(const bf16x8*)&Ab[(row * 16 + l) * 8];
            }
#pragma unroll
            for (int fm = 0; fm < 4; ++fm)
#pragma unroll
                for (int fn = 0; fn < 2; ++fn)
                    acc[fm][fn] = __builtin_amdgcn_mfma_f32_16x16x32_bf16(
                        af[fm], B[kc][fn], acc[fm][fn], 0, 0, 0);
        }
    };

    bf16x8 B0[4][2], B1[4][2];
    stageA(0, 0);
    loadB(B0, 0);

    for (int k0 = 0; k0 < H; k0 += 2 * BK) {
        __syncthreads();                          // drains A(k0) stage + B0
        if (k0 + BK < H) { loadB(B1, k0 + BK); stageA(1, k0 + BK); }
        compute(As[0], B0);

        __syncthreads();                          // drains A(k0+BK) + B1
        if (k0 + 2 * BK < H) { loadB(B0, k0 + 2 * BK); stageA(0, k0 + 2 * BK); }
        compute(As[1], B1);
    }

    // epilogue: z += Whx[i]*x[b,t] + bh[i]; tanh; store bf16.
    // C layout (16x16x32): col = lane&15, row = quad*4 + reg  [m89-verified]
#pragma unroll
    for (int fm = 0; fm < 4; ++fm) {
        int rb = bm0 + qm + fm * 16 + quad * 4;
        float xv[4];
#pragma unroll
        for (int r = 0; r < 4; ++r) xv[r] = x[(size_t)(rb + r) * TT + t];
#pragma unroll
        for (int fn = 0; fn < 2; ++fn) {
            int col = bn0 + qn + fn * 16 + lrow;
            float wx = Whx[col], bb = bh[col];
#pragma unroll
            for (int r = 0; r < 4; ++r) {
                float z = acc[fm][fn][r] + wx * xv[r] + bb;
                Sw[(size_t)(rb + r) * H + col] = (bf16)tanhf(z);
            }
        }
    }
}

// ---------------------------------------------------------------------------
// out[b,c] = sum_h Why[h,c] * S[b,h] + bp[c]   (S = h_T^T, [B,H] bf16)
// one block per batch row
// ---------------------------------------------------------------------------
__global__ void out_proj(const bf16* __restrict__ S,
                         const float* __restrict__ Why,   // [H, C]
                         const float* __restrict__ bp,    // [C]
                         float* __restrict__ out) {       // [B, C]
    int b = blockIdx.x, tid = threadIdx.x;
    float p[NC];
#pragma unroll
    for (int c = 0; c < NC; ++c) p[c] = 0.f;
    for (int h = tid; h < H; h += 256) {
        float s = (float)S[(size_t)b * H + h];
        const float* wr = Why + h * NC;
#pragma unroll
        for (int c = 0; c < NC; ++c) p[c] += s * wr[c];
    }
    __shared__ float red[256 * NC];
#pragma unroll
    for (int c = 0; c < NC; ++c) red[tid * NC + c] = p[c];
    __syncthreads();
    for (int s = 128; s > 0; s >>= 1) {
        if (tid < s)
#pragma unroll
            for (int c = 0; c < NC; ++c) red[tid * NC + c] += red[(tid + s) * NC + c];
        __syncthreads();
    }
    if (tid < NC) out[(size_t)b * NC + tid] = red[tid] + bp[tid];
}

// ---------------------------------------------------------------------------
extern "C" void kernel_launch(void* const* d_in, const int* in_sizes, int n_in,
                              void* d_out, int out_size, void* d_ws, size_t ws_size,
                              hipStream_t stream) {
    const float* x   = (const float*)d_in[0];   // [B, T]
    const float* Whx = (const float*)d_in[1];   // [H, 1]
    const float* Whh = (const float*)d_in[2];   // [H, H]
    const float* Why = (const float*)d_in[3];   // [H, C]
    const float* bh  = (const float*)d_in[4];   // [H, 1]
    const float* bp  = (const float*)d_in[5];   // [C, 1]
    float* out = (float*)d_out;

    // workspace: Wshuf (8 MB) | S0 (8 MB) | S1 (8 MB)
    bf16* Wshuf = (bf16*)d_ws;
    bf16* S0 = (bf16*)((char*)d_ws + (size_t)8 * 1024 * 1024);
    bf16* S1 = (bf16*)((char*)d_ws + (size_t)16 * 1024 * 1024);

    hipLaunchKernelGGL(w_shuffle_kernel, dim3((H * H / 8) / 256), dim3(256),
                       0, stream, Whh, Wshuf);

    // t = 0 writes S1; step t reads (t&1 ? S1 : S0), writes the other.
    hipLaunchKernelGGL(rnn_init, dim3(BB), dim3(256), 0, stream, x, Whx, bh, S1);

    for (int t = 1; t < TT; ++t) {
        const bf16* Srd = (t & 1) ? S1 : S0;
        bf16*       Swr = (t & 1) ? S0 : S1;
        hipLaunchKernelGGL(rnn_step, dim3(512), dim3(256), 0, stream,
                           x, Whx, bh, Wshuf, Srd, Swr, t);
    }

    // t=63 (odd) wrote S0
    hipLaunchKernelGGL(out_proj, dim3(BB), dim3(256), 0, stream, S0, Why, bp, out);
}